// Round 8
// baseline (198.245 us; speedup 1.0000x reference)
//
#include <hip/hip_runtime.h>
#include <hip/hip_bf16.h>
#include <stdint.h>

#define IN_F 4096
#define OUT_F 4096
#define THRESH 0.01f

typedef unsigned int u32;
typedef unsigned short u16;
typedef unsigned long long u64;
typedef __attribute__((ext_vector_type(8))) short short8;   // 8 bf16 = 4 VGPR
typedef __attribute__((ext_vector_type(4))) float f32x4;

// ws layout:
//   [0)        u16 xB[512][64][8]        (512 KB)  B-frag layout: ((k>>3)*64+b)*8+(k&7)
//   [524288)   u16 Wd[4096][4096]        (32 MiB)  dense bf16 weight, row-major
static const size_t WS_XB = 0;
static const size_t WS_WD = 524288;
static const size_t WS_NEEDED = WS_WD + (size_t)OUT_F * IN_F * 2;

static __device__ __forceinline__ u16 f2bf(float v) {
  __hip_bfloat16 h = __float2bfloat16(v);
  return *reinterpret_cast<u16*>(&h);
}

// gate + bf16 + MFMA-B-fragment layout: xB[((k>>3)*64 + b)*8 + (k&7)] = bf16(gate(x[b][k]))
__global__ __launch_bounds__(256) void k_xb(const float* __restrict__ x, u16* __restrict__ xB) {
  const int tid = blockIdx.x * 256 + threadIdx.x;   // 32768 threads
  const int b = tid & 63;
  const int kg = tid >> 6;                          // 0..511
  const float* src = x + (size_t)b * IN_F + kg * 8;
  const f32x4 a0 = *reinterpret_cast<const f32x4*>(src);
  const f32x4 a1 = *reinterpret_cast<const f32x4*>(src + 4);
  short8 o;
#pragma unroll
  for (int e = 0; e < 4; ++e) {
    float v = a0[e]; v = (v > THRESH) ? v : 0.0f; o[e] = (short)f2bf(v);
  }
#pragma unroll
  for (int e = 0; e < 4; ++e) {
    float v = a1[e]; v = (v > THRESH) ? v : 0.0f; o[4 + e] = (short)f2bf(v);
  }
  *reinterpret_cast<short8*>(xB + ((size_t)kg * 64 + b) * 8) = o;   // coalesced 16B
}

// zero the dense W (32 MiB): 2048 blocks x 1024 threads x 16 B
__global__ __launch_bounds__(1024) void k_zero(uint4* __restrict__ wd) {
  wd[(size_t)blockIdx.x * 1024u + threadIdx.x] = make_uint4(0u, 0u, 0u, 0u);
}

// COO -> dense W via hardware packed-bf16 global atomics (fire-and-forget, no return)
__global__ __launch_bounds__(256) void k_wscat(const int* __restrict__ rows,
                                               const int* __restrict__ cols,
                                               const float* __restrict__ vals,
                                               int nnz, u16* __restrict__ wd) {
  const u32 base = blockIdx.x * 2048u + threadIdx.x;
#pragma unroll
  for (int j = 0; j < 8; ++j) {
    const u32 i = base + (u32)j * 256u;
    if (i < (u32)nnz) {
      const u32 r = (u32)rows[i] & (OUT_F - 1);
      const u32 c = (u32)cols[i] & (IN_F - 1);
      const u32 pk = (u32)f2bf(vals[i]) << ((c & 1u) * 16u);  // {lo,hi} bf16 pair
      u16* addr = wd + ((size_t)r * IN_F + (c & ~1u));
      asm volatile("global_atomic_pk_add_bf16 %0, %1, off"
                   :: "v"((u64)(uintptr_t)addr), "v"(pk) : "memory");
    }
  }
}

// skinny GEMM: out[b][r] = sum_k Wd[r][k]*xB[k][b] + bias[r]
// one block per 16-row tile; 16 waves split K (256 each); A straight from global
// (lanes {r,r+16,r+32,r+48} cover one 64B sector of row r -> full sector use);
// fragment mapping + epilogue identical to the HW-proven rounds 5-7 kernel.
__global__ __launch_bounds__(1024) void k_gemm(const u16* __restrict__ wd,
                                               const u16* __restrict__ xB,
                                               const float* __restrict__ bias,
                                               float* __restrict__ out) {
  __shared__ float R[16 * 1024];   // 64 KB reduction scratch
  const int tid = threadIdx.x;
  const int lane = tid & 63;
  const int w = tid >> 6;          // wave 0..15: K range [w*256, w*256+256)
  const u32 t = blockIdx.x;
  const int row = lane & 15;       // A row / C col
  const int e8 = (lane >> 4) * 8;  // k sub-offset within 32

  f32x4 acc0 = {0.f, 0.f, 0.f, 0.f}, acc1 = {0.f, 0.f, 0.f, 0.f};
  f32x4 acc2 = {0.f, 0.f, 0.f, 0.f}, acc3 = {0.f, 0.f, 0.f, 0.f};
  const u16* arow = wd + ((size_t)(t * 16u + row)) * IN_F;
#pragma unroll
  for (int s = 0; s < 8; ++s) {
    const int kabs = w * 256 + s * 32 + e8;
    const short8 af = *reinterpret_cast<const short8*>(arow + kabs);   // 16B global
    const u16* bp = xB + (size_t)(kabs >> 3) * 512 + (u32)row * 8;
    const short8 b0 = *reinterpret_cast<const short8*>(bp);
    const short8 b1 = *reinterpret_cast<const short8*>(bp + 128);
    const short8 b2 = *reinterpret_cast<const short8*>(bp + 256);
    const short8 b3 = *reinterpret_cast<const short8*>(bp + 384);
    acc0 = __builtin_amdgcn_mfma_f32_16x16x32_bf16(af, b0, acc0, 0, 0, 0);
    acc1 = __builtin_amdgcn_mfma_f32_16x16x32_bf16(af, b1, acc1, 0, 0, 0);
    acc2 = __builtin_amdgcn_mfma_f32_16x16x32_bf16(af, b2, acc2, 0, 0, 0);
    acc3 = __builtin_amdgcn_mfma_f32_16x16x32_bf16(af, b3, acc3, 0, 0, 0);
  }
  // per-wave C partials: R[((w*4+g)*16 + crow)*16 + ccol]
  {
    const int ccol = lane & 15;                 // C col = lane&15 (m89-verified)
    const int rb = (lane >> 4) * 4;             // C row = (lane>>4)*4 + reg
#pragma unroll
    for (int qq = 0; qq < 4; ++qq) R[((w * 4 + 0) * 16 + rb + qq) * 16 + ccol] = acc0[qq];
#pragma unroll
    for (int qq = 0; qq < 4; ++qq) R[((w * 4 + 1) * 16 + rb + qq) * 16 + ccol] = acc1[qq];
#pragma unroll
    for (int qq = 0; qq < 4; ++qq) R[((w * 4 + 2) * 16 + rb + qq) * 16 + ccol] = acc2[qq];
#pragma unroll
    for (int qq = 0; qq < 4; ++qq) R[((w * 4 + 3) * 16 + rb + qq) * 16 + ccol] = acc3[qq];
  }
  __syncthreads();
  // reduce 16 K-partials -> out(row rl, batch b); coalesced 64B store runs
  const int rl = tid & 15;
  const int b = tid >> 4;
  float sum = bias[t * 16u + rl];
#pragma unroll
  for (int w2 = 0; w2 < 16; ++w2)
    sum += R[((w2 * 4 + (b >> 4)) * 16 + rl) * 16 + (b & 15)];
  out[(size_t)b * OUT_F + t * 16u + rl] = sum;
}

// ---- fallback path (only if ws too small): correct but slow ----
__global__ __launch_bounds__(256) void k_bias_init(const float* __restrict__ bias,
                                                   float* __restrict__ out) {
  const int i = blockIdx.x * 256 + threadIdx.x;
  if (i < 64 * OUT_F) out[i] = bias[i & (OUT_F - 1)];
}

__global__ __launch_bounds__(256) void k_fallback(const int* __restrict__ rows,
                                                  const int* __restrict__ cols,
                                                  const float* __restrict__ vals,
                                                  const float* __restrict__ x,
                                                  float* __restrict__ out, int nnz) {
  const int gw = (int)(((u32)blockIdx.x * blockDim.x + threadIdx.x) >> 6);
  const int lane = threadIdx.x & 63;
  const int nw = (int)(((u32)gridDim.x * blockDim.x) >> 6);
  for (int i = gw; i < nnz; i += nw) {
    const int r = rows[i];
    const int c = cols[i];
    const float v = vals[i];
    const float xv = x[lane * IN_F + c];
    if (xv > THRESH) atomicAdd(&out[(size_t)lane * OUT_F + r], v * xv);
  }
}

extern "C" void kernel_launch(void* const* d_in, const int* in_sizes, int n_in,
                              void* d_out, int out_size, void* d_ws, size_t ws_size,
                              hipStream_t stream) {
  const float* x = (const float*)d_in[0];
  const int* rows = (const int*)d_in[1];
  const int* cols = (const int*)d_in[2];
  const float* vals = (const float*)d_in[3];
  const float* bias = (const float*)d_in[4];
  float* out = (float*)d_out;
  const int nnz = in_sizes[1];

  if (ws_size >= WS_NEEDED) {
    u16* xB = (u16*)((char*)d_ws + WS_XB);
    u16* wd = (u16*)((char*)d_ws + WS_WD);
    k_xb<<<128, 256, 0, stream>>>(x, xB);
    k_zero<<<2048, 1024, 0, stream>>>((uint4*)wd);
    k_wscat<<<(nnz + 2047) / 2048, 256, 0, stream>>>(rows, cols, vals, nnz, wd);
    k_gemm<<<OUT_F / 16, 1024, 0, stream>>>(wd, xB, bias, out);
  } else {
    k_bias_init<<<(64 * OUT_F + 255) / 256, 256, 0, stream>>>(bias, out);
    k_fallback<<<4096, 256, 0, stream>>>(rows, cols, vals, x, out, nnz);
  }
}

// Round 10
// 61.868 us; speedup vs baseline: 3.2043x; 3.2043x over previous
//
#include <hip/hip_runtime.h>
#include <hip/hip_bf16.h>
#include <stdint.h>

#define IN_F 4096
#define OUT_F 4096
#define NBKT 256
#define SBLOCKS 410          // 410 * 8192 = 3,358,720 >= NNZ
#define REC_PER_SB 8192
#define SMAX 14336u          // per-bucket cap: mean 13107, sigma 113, +10.8 sigma
#define THRESH 0.01f

typedef unsigned int u32;
typedef unsigned short u16;
typedef unsigned char u8;
typedef __attribute__((ext_vector_type(8))) short short8;   // 8 bf16 = 4 VGPR
typedef __attribute__((ext_vector_type(4))) float f32x4;

// ws layout — offsets DERIVED, 256B-padded (round-9 bug: hand-computed literals overlapped)
static constexpr size_t pad256(size_t x) { return (x + 255u) & ~(size_t)255u; }
static constexpr size_t WS_XB    = 0;                                            // u16 xB[512][64][8]
static constexpr size_t WS_OFFA  = pad256(WS_XB + (size_t)512 * 64 * 8 * 2);     // u32 offA[410][257]
static constexpr size_t WS_SORT  = pad256(WS_OFFA + (size_t)SBLOCKS * (NBKT + 1) * 4);  // u32 sortg[410][8192]
static constexpr size_t WS_SORTB = pad256(WS_SORT + (size_t)SBLOCKS * REC_PER_SB * 4);  // u8 sortgb[410][8192]
static constexpr size_t WS_GOFF  = pad256(WS_SORTB + (size_t)SBLOCKS * REC_PER_SB);     // u32 gOff[256][410]
static constexpr size_t WS_NTOT  = pad256(WS_GOFF + (size_t)NBKT * SBLOCKS * 4);        // u32 ntot[256]
static constexpr size_t WS_BINS  = pad256(WS_NTOT + (size_t)NBKT * 4);                  // u32 sortb[256][SMAX]
static constexpr size_t WS_NEEDED = WS_BINS + (size_t)NBKT * SMAX * 4;

static __device__ __forceinline__ u16 f2bf(float v) {
  __hip_bfloat16 h = __float2bfloat16(v);
  return *reinterpret_cast<u16*>(&h);
}

// gate + bf16 + MFMA-B-fragment layout: xB[((k>>3)*64 + b)*8 + (k&7)] = bf16(gate(x[b][k]))
__global__ __launch_bounds__(256) void k_xb(const float* __restrict__ x, u16* __restrict__ xB) {
  const int tid = blockIdx.x * 256 + threadIdx.x;   // 32768 threads
  const int b = tid & 63;
  const int kg = tid >> 6;                          // 0..511
  const float* src = x + (size_t)b * IN_F + kg * 8;
  const f32x4 a0 = *reinterpret_cast<const f32x4*>(src);
  const f32x4 a1 = *reinterpret_cast<const f32x4*>(src + 4);
  short8 o;
#pragma unroll
  for (int e = 0; e < 4; ++e) {
    float v = a0[e]; v = (v > THRESH) ? v : 0.0f; o[e] = (short)f2bf(v);
  }
#pragma unroll
  for (int e = 0; e < 4; ++e) {
    float v = a1[e]; v = (v > THRESH) ? v : 0.0f; o[4 + e] = (short)f2bf(v);
  }
  *reinterpret_cast<short8*>(xB + ((size_t)kg * 64 + b) * 8) = o;   // coalesced 16B
}

// block-major counting sort (round-6 proven) + parallel u8 bucket-id array
__global__ __launch_bounds__(1024) void k_scatter(const int* __restrict__ rows,
                                                  const int* __restrict__ cols,
                                                  const float* __restrict__ vals, u32 nnz,
                                                  u32* __restrict__ offA,
                                                  u32* __restrict__ sortg,
                                                  u8* __restrict__ sortgb) {
  __shared__ u32 cnt[NBKT];
  __shared__ u32 pref[NBKT + 1];
  __shared__ u32 srt[REC_PER_SB];   // 32 KB
  __shared__ __attribute__((aligned(16))) u8 srtb[REC_PER_SB];   // 8 KB
  const int tid = threadIdx.x;
  const int lane = tid & 63;
  const int wid = tid >> 6;
  if (tid < NBKT) cnt[tid] = 0;
  __syncthreads();
  const u32 base = blockIdx.x * (u32)REC_PER_SB;
  u32 rec[8], bkt[8], rk[8];
#pragma unroll
  for (int j = 0; j < 8; ++j) {
    const u32 i = base + (u32)j * 1024u + tid;
    bkt[j] = 0xffffffffu;
    if (i < nnz) {
      const u32 r = (u32)rows[i] & 4095u;
      const u32 c = (u32)cols[i] & 4095u;
      rec[j] = (c << 20) | ((r & 15u) << 16) | (u32)f2bf(vals[i]);
      bkt[j] = r >> 4;
      rk[j] = atomicAdd(&cnt[bkt[j]], 1u);
    }
  }
  __syncthreads();
  // wave-0 exclusive prefix over 256 bins (4 bins/lane + wave scan)
  if (wid == 0) {
    u32 a[4]; u32 s = 0;
#pragma unroll
    for (int j = 0; j < 4; ++j) { a[j] = cnt[lane * 4 + j]; s += a[j]; }
    u32 x = s;
#pragma unroll
    for (int d = 1; d < 64; d <<= 1) {
      const u32 y = (u32)__shfl_up((int)x, d, 64);
      if (lane >= d) x += y;
    }
    u32 e = x - s;
#pragma unroll
    for (int j = 0; j < 4; ++j) { pref[lane * 4 + j] = e; e += a[j]; }
    if (lane == 63) pref[256] = e;   // block total
  }
  __syncthreads();
#pragma unroll
  for (int j = 0; j < 8; ++j)
    if (bkt[j] != 0xffffffffu) {
      const u32 pos = pref[bkt[j]] + rk[j];
      srt[pos] = rec[j];
      srtb[pos] = (u8)bkt[j];
    }
  if (tid < NBKT + 1) offA[(size_t)blockIdx.x * (NBKT + 1) + tid] = pref[tid];
  __syncthreads();
  // coalesced dumps (garbage beyond total: never read)
  u32* dst = sortg + (size_t)blockIdx.x * REC_PER_SB;
#pragma unroll
  for (int j = 0; j < 2; ++j) {
    const int o = j * 4096 + tid * 4;
    *reinterpret_cast<uint4*>(&dst[o]) = *reinterpret_cast<uint4*>(&srt[o]);
  }
  if (tid < 512) {
    uint4* bdst = (uint4*)(sortgb + (size_t)blockIdx.x * REC_PER_SB);
    bdst[tid] = *reinterpret_cast<uint4*>(&srtb[tid * 16]);
  }
}

// per-bucket exclusive scan of the 410 run lengths -> exact global destinations
__global__ __launch_bounds__(512) void k_goff(const u32* __restrict__ offA,
                                              u32* __restrict__ gOff,
                                              u32* __restrict__ ntot) {
  __shared__ u32 wsum[8];
  const int t = blockIdx.x;          // bucket
  const int tid = threadIdx.x;       // 0..511
  const int lane = tid & 63, w = tid >> 6;
  u32 v = 0;
  if (tid < SBLOCKS)
    v = offA[(size_t)tid * (NBKT + 1) + t + 1] - offA[(size_t)tid * (NBKT + 1) + t];
  u32 x = v;
#pragma unroll
  for (int d = 1; d < 64; d <<= 1) {
    const u32 y = (u32)__shfl_up((int)x, d, 64);
    if (lane >= d) x += y;
  }
  if (lane == 63) wsum[w] = x;
  __syncthreads();
  u32 bse = 0;
  for (int i = 0; i < w; ++i) bse += wsum[i];
  const u32 excl = bse + x - v;
  if (tid < SBLOCKS) gOff[(size_t)t * SBLOCKS + tid] = excl;
  if (tid == SBLOCKS - 1) ntot[t] = excl + v;
}

// block-major -> bucket-major contiguous (run-granular writes, ~32-record runs)
__global__ __launch_bounds__(1024) void k_reorder(const u32* __restrict__ sortg,
                                                  const u8* __restrict__ sortgb,
                                                  const u32* __restrict__ offA,
                                                  const u32* __restrict__ gOff,
                                                  u32* __restrict__ sortb) {
  __shared__ u32 pref[NBKT + 1];
  __shared__ u32 gof[NBKT];
  const int blk = blockIdx.x;
  const int tid = threadIdx.x;
  if (tid < NBKT + 1) pref[tid] = offA[(size_t)blk * (NBKT + 1) + tid];
  if (tid < NBKT) gof[tid] = gOff[(size_t)tid * SBLOCKS + blk];
  __syncthreads();
  const u32 tot = pref[NBKT];
  const u32* src = sortg + (size_t)blk * REC_PER_SB;
  const u8* srcb = sortgb + (size_t)blk * REC_PER_SB;
#pragma unroll
  for (int j = 0; j < 8; ++j) {
    const u32 i = (u32)j * 1024u + tid;
    if (i < tot) {
      const u32 r = src[i];
      const u32 t = srcb[i];
      const u32 d = t * SMAX + gof[t] + (i - pref[t]);
      sortb[d] = r;
    }
  }
}

// one block per bucket: coalesced record stream -> quarter densify -> MFMA
__global__ __launch_bounds__(1024, 1) void k_accum(const u32* __restrict__ sortb,
                                                   const u32* __restrict__ ntot,
                                                   const u16* __restrict__ xB,
                                                   const float* __restrict__ bias,
                                                   float* __restrict__ out) {
  __shared__ float W[16 * 1024];    // 64 KB; reused as reduction scratch at the end
  const int tid = threadIdx.x;
  const int lane = tid & 63;
  const int w = tid >> 6;           // wave 0..15
  const u32 t = blockIdx.x;
  u32 n = ntot[t];
  if (n > SMAX) n = SMAX;
  const u32* bin = sortb + (size_t)t * SMAX;
  // coalesced preload of the whole bucket to VGPRs
  u32 rec[14];
#pragma unroll
  for (int j = 0; j < 14; ++j) {
    const u32 i = (u32)j * 1024u + tid;
    rec[j] = (i < n) ? bin[i] : 0u;
  }

  f32x4 acc0 = {0.f, 0.f, 0.f, 0.f}, acc1 = {0.f, 0.f, 0.f, 0.f};
  f32x4 acc2 = {0.f, 0.f, 0.f, 0.f}, acc3 = {0.f, 0.f, 0.f, 0.f};
  const int row = lane & 15;       // A-frag row / C col index
  const int e8 = (lane >> 4) * 8;  // A/B-frag k sub-offset

  for (int q = 0; q < 4; ++q) {
    __syncthreads();               // previous quarter's A-reads done before re-zero
    const f32x4 z = {0.f, 0.f, 0.f, 0.f};
#pragma unroll
    for (int j = 0; j < 4; ++j)
      *reinterpret_cast<f32x4*>(&W[j * 4096 + tid * 4]) = z;
    __syncthreads();
    // scatter-add this quarter's records (f32: exact duplicate handling)
    // swizzle at 8-ELEMENT granularity: XOR bits >=3 only, so any aligned
    // 8-run [klb, klb+8) maps to the physical 8-run [klb^xor, klb^xor+8).
#pragma unroll
    for (int j = 0; j < 14; ++j) {
      const u32 i = (u32)j * 1024u + tid;
      if (i < n) {
        const u32 rc = rec[j];
        if ((rc >> 30) == (u32)q) {
          const u32 rl = (rc >> 16) & 15u;
          const u32 cl = ((rc >> 20) & 1023u) ^ ((rl & 7u) << 3);   // 8-elem XOR swizzle
          __hip_atomic_fetch_add(&W[rl * 1024u + cl], __uint_as_float(rc << 16),
                                 __ATOMIC_RELAXED, __HIP_MEMORY_SCOPE_WORKGROUP);
        }
      }
    }
    __syncthreads();
    // dense MFMA over this quarter; wave w covers local k [w*64, w*64+64)
#pragma unroll
    for (int s = 0; s < 2; ++s) {
      const int klb = w * 64 + s * 32 + e8;                 // 8-aligned local k
      const int sw = klb ^ ((row & 7) << 3);                // matches write swizzle
      const f32x4 wa = *reinterpret_cast<const f32x4*>(&W[row * 1024 + sw]);
      const f32x4 wb = *reinterpret_cast<const f32x4*>(&W[row * 1024 + (sw + 4)]);
      short8 af;
#pragma unroll
      for (int e = 0; e < 4; ++e) af[e] = (short)f2bf(wa[e]);
#pragma unroll
      for (int e = 0; e < 4; ++e) af[4 + e] = (short)f2bf(wb[e]);
      const int kabs = q * 1024 + klb;
      const u16* bp = xB + (size_t)(kabs >> 3) * 512 + (u32)row * 8;
      const short8 b0 = *reinterpret_cast<const short8*>(bp);
      const short8 b1 = *reinterpret_cast<const short8*>(bp + 128);
      const short8 b2 = *reinterpret_cast<const short8*>(bp + 256);
      const short8 b3 = *reinterpret_cast<const short8*>(bp + 384);
      acc0 = __builtin_amdgcn_mfma_f32_16x16x32_bf16(af, b0, acc0, 0, 0, 0);
      acc1 = __builtin_amdgcn_mfma_f32_16x16x32_bf16(af, b1, acc1, 0, 0, 0);
      acc2 = __builtin_amdgcn_mfma_f32_16x16x32_bf16(af, b2, acc2, 0, 0, 0);
      acc3 = __builtin_amdgcn_mfma_f32_16x16x32_bf16(af, b3, acc3, 0, 0, 0);
    }
  }
  __syncthreads();
  // write per-wave C partials to scratch: scr[((w*4+g)*16 + crow)*16 + ccol]
  {
    const int ccol = lane & 15;                 // C col = lane&15 (m89-verified)
    const int rb = (lane >> 4) * 4;             // C row = (lane>>4)*4 + reg
#pragma unroll
    for (int qq = 0; qq < 4; ++qq) W[((w * 4 + 0) * 16 + rb + qq) * 16 + ccol] = acc0[qq];
#pragma unroll
    for (int qq = 0; qq < 4; ++qq) W[((w * 4 + 1) * 16 + rb + qq) * 16 + ccol] = acc1[qq];
#pragma unroll
    for (int qq = 0; qq < 4; ++qq) W[((w * 4 + 2) * 16 + rb + qq) * 16 + ccol] = acc2[qq];
#pragma unroll
    for (int qq = 0; qq < 4; ++qq) W[((w * 4 + 3) * 16 + rb + qq) * 16 + ccol] = acc3[qq];
  }
  __syncthreads();
  // reduce 16 wave-partials -> out(row rl, batch b); coalesced 64B store runs
  const int rl = tid & 15;
  const int b = tid >> 4;
  float sum = bias[t * 16u + rl];
#pragma unroll
  for (int w2 = 0; w2 < 16; ++w2)
    sum += W[((w2 * 4 + (b >> 4)) * 16 + rl) * 16 + (b & 15)];
  out[(size_t)b * OUT_F + t * 16u + rl] = sum;
}

// ---- fallback path (only if ws too small): correct but slow ----
__global__ __launch_bounds__(256) void k_bias_init(const float* __restrict__ bias,
                                                   float* __restrict__ out) {
  const int i = blockIdx.x * 256 + threadIdx.x;
  if (i < 64 * OUT_F) out[i] = bias[i & (OUT_F - 1)];
}

__global__ __launch_bounds__(256) void k_fallback(const int* __restrict__ rows,
                                                  const int* __restrict__ cols,
                                                  const float* __restrict__ vals,
                                                  const float* __restrict__ x,
                                                  float* __restrict__ out, int nnz) {
  const int gw = (int)(((u32)blockIdx.x * blockDim.x + threadIdx.x) >> 6);
  const int lane = threadIdx.x & 63;
  const int nw = (int)(((u32)gridDim.x * blockDim.x) >> 6);
  for (int i = gw; i < nnz; i += nw) {
    const int r = rows[i];
    const int c = cols[i];
    const float v = vals[i];
    const float xv = x[lane * IN_F + c];
    if (xv > THRESH) atomicAdd(&out[(size_t)lane * OUT_F + r], v * xv);
  }
}

extern "C" void kernel_launch(void* const* d_in, const int* in_sizes, int n_in,
                              void* d_out, int out_size, void* d_ws, size_t ws_size,
                              hipStream_t stream) {
  const float* x = (const float*)d_in[0];
  const int* rows = (const int*)d_in[1];
  const int* cols = (const int*)d_in[2];
  const float* vals = (const float*)d_in[3];
  const float* bias = (const float*)d_in[4];
  float* out = (float*)d_out;
  const int nnz = in_sizes[1];

  if (ws_size >= WS_NEEDED && nnz <= SBLOCKS * REC_PER_SB) {
    u16* xB = (u16*)((char*)d_ws + WS_XB);
    u32* offA = (u32*)((char*)d_ws + WS_OFFA);
    u32* sortg = (u32*)((char*)d_ws + WS_SORT);
    u8* sortgb = (u8*)((char*)d_ws + WS_SORTB);
    u32* gOff = (u32*)((char*)d_ws + WS_GOFF);
    u32* ntot = (u32*)((char*)d_ws + WS_NTOT);
    u32* sortb = (u32*)((char*)d_ws + WS_BINS);
    k_xb<<<128, 256, 0, stream>>>(x, xB);
    k_scatter<<<SBLOCKS, 1024, 0, stream>>>(rows, cols, vals, (u32)nnz, offA, sortg, sortgb);
    k_goff<<<NBKT, 512, 0, stream>>>(offA, gOff, ntot);
    k_reorder<<<SBLOCKS, 1024, 0, stream>>>(sortg, sortgb, offA, gOff, sortb);
    k_accum<<<NBKT, 1024, 0, stream>>>(sortb, ntot, xB, bias, out);
  } else {
    k_bias_init<<<(64 * OUT_F + 255) / 256, 256, 0, stream>>>(bias, out);
    k_fallback<<<4096, 256, 0, stream>>>(rows, cols, vals, x, out, nnz);
  }
}

// Round 11
// 57.111 us; speedup vs baseline: 3.4712x; 1.0833x over previous
//
#include <hip/hip_runtime.h>
#include <hip/hip_bf16.h>
#include <stdint.h>

#define IN_F 4096
#define OUT_F 4096
#define NBKT 256
#define SBLOCKS 410          // 410 * 8192 = 3,358,720 >= NNZ
#define REC_PER_SB 8192
#define SMAX 14336u          // per-bucket cap: mean 13107, sigma 114, +10.8 sigma
#define THRESH 0.01f

typedef unsigned int u32;
typedef unsigned short u16;
typedef unsigned char u8;
typedef __attribute__((ext_vector_type(8))) short short8;   // 8 bf16 = 4 VGPR
typedef __attribute__((ext_vector_type(4))) float f32x4;

// ws layout — offsets DERIVED, 256B-padded
static constexpr size_t pad256(size_t x) { return (x + 255u) & ~(size_t)255u; }
static constexpr size_t WS_XB   = 0;                                           // u16 xB[512][64][8]
static constexpr size_t WS_CUR  = pad256(WS_XB + (size_t)512 * 64 * 8 * 2);    // u32 gcursor[256]
static constexpr size_t WS_BINS = pad256(WS_CUR + (size_t)NBKT * 4);           // u32 sortb[256][SMAX]
static constexpr size_t WS_NEEDED = WS_BINS + (size_t)NBKT * SMAX * 4;

static __device__ __forceinline__ u16 f2bf(float v) {
  __hip_bfloat16 h = __float2bfloat16(v);
  return *reinterpret_cast<u16*>(&h);
}

__global__ __launch_bounds__(256) void k_init(u32* __restrict__ gcursor) {
  gcursor[threadIdx.x] = 0u;
}

// fused: [blocks 0..31: gate+bf16+B-frag xB] + per-block 256-bucket LDS counting
// sort of 8192 COO records + cursor-reserved bucket-major contiguous dump.
__global__ __launch_bounds__(1024) void k_scatter(const int* __restrict__ rows,
                                                  const int* __restrict__ cols,
                                                  const float* __restrict__ vals, u32 nnz,
                                                  const float* __restrict__ x,
                                                  u16* __restrict__ xB,
                                                  u32* __restrict__ gcursor,
                                                  u32* __restrict__ sortb) {
  __shared__ u32 cnt[NBKT];
  __shared__ u32 pref[NBKT + 1];
  __shared__ u32 gbase[NBKT];
  __shared__ u32 srt[REC_PER_SB];   // 32 KB
  __shared__ u8 srtb[REC_PER_SB];   // 8 KB
  const int tid = threadIdx.x;
  const int lane = tid & 63;
  const int wid = tid >> 6;

  // fused xB build: 32 blocks x 1024 threads == 32768 slots (b = g&63, kg = g>>6)
  if (blockIdx.x < 32) {
    const int g = blockIdx.x * 1024 + tid;
    const int b = g & 63;
    const int kg = g >> 6;
    const float* src = x + (size_t)b * IN_F + kg * 8;
    const f32x4 a0 = *reinterpret_cast<const f32x4*>(src);
    const f32x4 a1 = *reinterpret_cast<const f32x4*>(src + 4);
    short8 o;
#pragma unroll
    for (int e = 0; e < 4; ++e) {
      float v = a0[e]; v = (v > THRESH) ? v : 0.0f; o[e] = (short)f2bf(v);
    }
#pragma unroll
    for (int e = 0; e < 4; ++e) {
      float v = a1[e]; v = (v > THRESH) ? v : 0.0f; o[4 + e] = (short)f2bf(v);
    }
    *reinterpret_cast<short8*>(xB + ((size_t)kg * 64 + b) * 8) = o;
  }

  if (tid < NBKT) cnt[tid] = 0;
  __syncthreads();
  const u32 base_i = blockIdx.x * (u32)REC_PER_SB;
  u32 rec[8], bkt[8], rk[8];
#pragma unroll
  for (int j = 0; j < 8; ++j) {
    const u32 i = base_i + (u32)j * 1024u + tid;
    bkt[j] = 0xffffffffu;
    if (i < nnz) {
      const u32 r = (u32)rows[i] & 4095u;
      const u32 c = (u32)cols[i] & 4095u;
      rec[j] = (c << 20) | ((r & 15u) << 16) | (u32)f2bf(vals[i]);
      bkt[j] = r >> 4;
      rk[j] = atomicAdd(&cnt[bkt[j]], 1u);
    }
  }
  __syncthreads();
  // wave-0 exclusive prefix over 256 bins (4 bins/lane + wave scan)
  if (wid == 0) {
    u32 a[4]; u32 s = 0;
#pragma unroll
    for (int j = 0; j < 4; ++j) { a[j] = cnt[lane * 4 + j]; s += a[j]; }
    u32 xx = s;
#pragma unroll
    for (int d = 1; d < 64; d <<= 1) {
      const u32 y = (u32)__shfl_up((int)xx, d, 64);
      if (lane >= d) xx += y;
    }
    u32 e = xx - s;
#pragma unroll
    for (int j = 0; j < 4; ++j) { pref[lane * 4 + j] = e; e += a[j]; }
    if (lane == 63) pref[256] = e;   // block total
  }
  __syncthreads();
  // scattered LDS writes of sorted records + per-bucket global reservation
#pragma unroll
  for (int j = 0; j < 8; ++j)
    if (bkt[j] != 0xffffffffu) {
      const u32 pos = pref[bkt[j]] + rk[j];
      srt[pos] = rec[j];
      srtb[pos] = (u8)bkt[j];
    }
  if (tid < NBKT) {
    const u32 len = pref[tid + 1] - pref[tid];
    gbase[tid] = len ? atomicAdd(&gcursor[tid], len) : 0u;
  }
  __syncthreads();
  // run-contiguous dump: consecutive i within a run -> consecutive global dest
  const u32 tot = pref[NBKT];
#pragma unroll
  for (int j = 0; j < 8; ++j) {
    const u32 i = (u32)j * 1024u + tid;
    if (i < tot) {
      const u32 t = srtb[i];
      const u32 off = gbase[t] + (i - pref[t]);
      if (off < SMAX) sortb[(size_t)t * SMAX + off] = srt[i];   // +10.8-sigma guard
    }
  }
}

// one block per bucket: coalesced record stream -> quarter densify -> MFMA
__global__ __launch_bounds__(1024, 1) void k_accum(const u32* __restrict__ sortb,
                                                   const u32* __restrict__ ntot,
                                                   const u16* __restrict__ xB,
                                                   const float* __restrict__ bias,
                                                   float* __restrict__ out) {
  __shared__ float W[16 * 1024];    // 64 KB; reused as reduction scratch at the end
  const int tid = threadIdx.x;
  const int lane = tid & 63;
  const int w = tid >> 6;           // wave 0..15
  const u32 t = blockIdx.x;
  u32 n = ntot[t];
  if (n > SMAX) n = SMAX;
  const u32* bin = sortb + (size_t)t * SMAX;
  // coalesced preload of the whole bucket to VGPRs
  u32 rec[14];
#pragma unroll
  for (int j = 0; j < 14; ++j) {
    const u32 i = (u32)j * 1024u + tid;
    rec[j] = (i < n) ? bin[i] : 0u;
  }

  f32x4 acc0 = {0.f, 0.f, 0.f, 0.f}, acc1 = {0.f, 0.f, 0.f, 0.f};
  f32x4 acc2 = {0.f, 0.f, 0.f, 0.f}, acc3 = {0.f, 0.f, 0.f, 0.f};
  const int row = lane & 15;       // A-frag row / C col index
  const int e8 = (lane >> 4) * 8;  // A/B-frag k sub-offset

  for (int q = 0; q < 4; ++q) {
    __syncthreads();               // previous quarter's A-reads done before re-zero
    const f32x4 z = {0.f, 0.f, 0.f, 0.f};
#pragma unroll
    for (int j = 0; j < 4; ++j)
      *reinterpret_cast<f32x4*>(&W[j * 4096 + tid * 4]) = z;
    __syncthreads();
    // scatter-add this quarter's records (f32: exact duplicate handling)
    // swizzle at 8-ELEMENT granularity: XOR bits >=3 only, so any aligned
    // 8-run [klb, klb+8) maps to the physical 8-run [klb^xor, klb^xor+8).
#pragma unroll
    for (int j = 0; j < 14; ++j) {
      const u32 i = (u32)j * 1024u + tid;
      if (i < n) {
        const u32 rc = rec[j];
        if ((rc >> 30) == (u32)q) {
          const u32 rl = (rc >> 16) & 15u;
          const u32 cl = ((rc >> 20) & 1023u) ^ ((rl & 7u) << 3);   // 8-elem XOR swizzle
          __hip_atomic_fetch_add(&W[rl * 1024u + cl], __uint_as_float(rc << 16),
                                 __ATOMIC_RELAXED, __HIP_MEMORY_SCOPE_WORKGROUP);
        }
      }
    }
    __syncthreads();
    // dense MFMA over this quarter; wave w covers local k [w*64, w*64+64)
#pragma unroll
    for (int s = 0; s < 2; ++s) {
      const int klb = w * 64 + s * 32 + e8;                 // 8-aligned local k
      const int sw = klb ^ ((row & 7) << 3);                // matches write swizzle
      const f32x4 wa = *reinterpret_cast<const f32x4*>(&W[row * 1024 + sw]);
      const f32x4 wb = *reinterpret_cast<const f32x4*>(&W[row * 1024 + (sw + 4)]);
      short8 af;
#pragma unroll
      for (int e = 0; e < 4; ++e) af[e] = (short)f2bf(wa[e]);
#pragma unroll
      for (int e = 0; e < 4; ++e) af[4 + e] = (short)f2bf(wb[e]);
      const int kabs = q * 1024 + klb;
      const u16* bp = xB + (size_t)(kabs >> 3) * 512 + (u32)row * 8;
      const short8 b0 = *reinterpret_cast<const short8*>(bp);
      const short8 b1 = *reinterpret_cast<const short8*>(bp + 128);
      const short8 b2 = *reinterpret_cast<const short8*>(bp + 256);
      const short8 b3 = *reinterpret_cast<const short8*>(bp + 384);
      acc0 = __builtin_amdgcn_mfma_f32_16x16x32_bf16(af, b0, acc0, 0, 0, 0);
      acc1 = __builtin_amdgcn_mfma_f32_16x16x32_bf16(af, b1, acc1, 0, 0, 0);
      acc2 = __builtin_amdgcn_mfma_f32_16x16x32_bf16(af, b2, acc2, 0, 0, 0);
      acc3 = __builtin_amdgcn_mfma_f32_16x16x32_bf16(af, b3, acc3, 0, 0, 0);
    }
  }
  __syncthreads();
  // write per-wave C partials to scratch: scr[((w*4+g)*16 + crow)*16 + ccol]
  {
    const int ccol = lane & 15;                 // C col = lane&15 (m89-verified)
    const int rb = (lane >> 4) * 4;             // C row = (lane>>4)*4 + reg
#pragma unroll
    for (int qq = 0; qq < 4; ++qq) W[((w * 4 + 0) * 16 + rb + qq) * 16 + ccol] = acc0[qq];
#pragma unroll
    for (int qq = 0; qq < 4; ++qq) W[((w * 4 + 1) * 16 + rb + qq) * 16 + ccol] = acc1[qq];
#pragma unroll
    for (int qq = 0; qq < 4; ++qq) W[((w * 4 + 2) * 16 + rb + qq) * 16 + ccol] = acc2[qq];
#pragma unroll
    for (int qq = 0; qq < 4; ++qq) W[((w * 4 + 3) * 16 + rb + qq) * 16 + ccol] = acc3[qq];
  }
  __syncthreads();
  // reduce 16 wave-partials -> out(row rl, batch b); coalesced 64B store runs
  const int rl = tid & 15;
  const int b = tid >> 4;
  float sum = bias[t * 16u + rl];
#pragma unroll
  for (int w2 = 0; w2 < 16; ++w2)
    sum += W[((w2 * 4 + (b >> 4)) * 16 + rl) * 16 + (b & 15)];
  out[(size_t)b * OUT_F + t * 16u + rl] = sum;
}

// ---- fallback path (only if ws too small): correct but slow ----
__global__ __launch_bounds__(256) void k_bias_init(const float* __restrict__ bias,
                                                   float* __restrict__ out) {
  const int i = blockIdx.x * 256 + threadIdx.x;
  if (i < 64 * OUT_F) out[i] = bias[i & (OUT_F - 1)];
}

__global__ __launch_bounds__(256) void k_fallback(const int* __restrict__ rows,
                                                  const int* __restrict__ cols,
                                                  const float* __restrict__ vals,
                                                  const float* __restrict__ x,
                                                  float* __restrict__ out, int nnz) {
  const int gw = (int)(((u32)blockIdx.x * blockDim.x + threadIdx.x) >> 6);
  const int lane = threadIdx.x & 63;
  const int nw = (int)(((u32)gridDim.x * blockDim.x) >> 6);
  for (int i = gw; i < nnz; i += nw) {
    const int r = rows[i];
    const int c = cols[i];
    const float v = vals[i];
    const float xv = x[lane * IN_F + c];
    if (xv > THRESH) atomicAdd(&out[(size_t)lane * OUT_F + r], v * xv);
  }
}

extern "C" void kernel_launch(void* const* d_in, const int* in_sizes, int n_in,
                              void* d_out, int out_size, void* d_ws, size_t ws_size,
                              hipStream_t stream) {
  const float* x = (const float*)d_in[0];
  const int* rows = (const int*)d_in[1];
  const int* cols = (const int*)d_in[2];
  const float* vals = (const float*)d_in[3];
  const float* bias = (const float*)d_in[4];
  float* out = (float*)d_out;
  const int nnz = in_sizes[1];

  if (ws_size >= WS_NEEDED && nnz <= SBLOCKS * REC_PER_SB) {
    u16* xB = (u16*)((char*)d_ws + WS_XB);
    u32* gcursor = (u32*)((char*)d_ws + WS_CUR);
    u32* sortb = (u32*)((char*)d_ws + WS_BINS);
    k_init<<<1, 256, 0, stream>>>(gcursor);
    k_scatter<<<SBLOCKS, 1024, 0, stream>>>(rows, cols, vals, (u32)nnz, x, xB,
                                            gcursor, sortb);
    k_accum<<<NBKT, 1024, 0, stream>>>(sortb, gcursor, xB, bias, out);
  } else {
    k_bias_init<<<(64 * OUT_F + 255) / 256, 256, 0, stream>>>(bias, out);
    k_fallback<<<4096, 256, 0, stream>>>(rows, cols, vals, x, out, nnz);
  }
}